// Round 2
// baseline (143.070 us; speedup 1.0000x reference)
//
#include <hip/hip_runtime.h>

#define TEMP 0.05f
#define EPS 1e-8f
#define NROWS 16384
#define DDIM 1024
// 4 waves/block, 2 rows/wave (half-wave per row) -> 8 rows/block
#define NBLOCKS (NROWS / 8)   // 2048

__global__ __launch_bounds__(256) void byol_rows_kernel(
        const float* __restrict__ a, const float* __restrict__ b,
        float* __restrict__ partials) {
    const int wave = threadIdx.x >> 6;
    const int lane = threadIdx.x & 63;
    const int half = lane >> 5;         // which row of the pair
    const int sub  = lane & 31;         // lane within the 32-lane row team
    const int row  = blockIdx.x * 8 + wave * 2 + half;

    const float4* a4 = (const float4*)(a + (size_t)row * DDIM);
    const float4* b4 = (const float4*)(b + (size_t)row * DDIM);

    // 16 outstanding float4 loads per lane before any dependent use.
    float4 av[8], bv[8];
#pragma unroll
    for (int j = 0; j < 8; ++j) av[j] = a4[sub + 32 * j];
#pragma unroll
    for (int j = 0; j < 8; ++j) bv[j] = b4[sub + 32 * j];

    float dot = 0.f, aa = 0.f, bb = 0.f;
#pragma unroll
    for (int j = 0; j < 8; ++j) {
        dot += av[j].x * bv[j].x + av[j].y * bv[j].y
             + av[j].z * bv[j].z + av[j].w * bv[j].w;
        aa  += av[j].x * av[j].x + av[j].y * av[j].y
             + av[j].z * av[j].z + av[j].w * av[j].w;
        bb  += bv[j].x * bv[j].x + bv[j].y * bv[j].y
             + bv[j].z * bv[j].z + bv[j].w * bv[j].w;
    }

    // Butterfly within each 32-lane half (xor offsets < 32 never cross halves).
#pragma unroll
    for (int off = 16; off > 0; off >>= 1) {
        dot += __shfl_xor(dot, off, 64);
        aa  += __shfl_xor(aa,  off, 64);
        bb  += __shfl_xor(bb,  off, 64);
    }

    __shared__ float s[8];
    if (sub == 0) {
        float n1 = fmaxf(sqrtf(aa), EPS);
        float n2 = fmaxf(sqrtf(bb), EPS);
        s[wave * 2 + half] = 2.0f - 2.0f * (dot / (n1 * n2));
    }
    __syncthreads();
    if (threadIdx.x == 0) {
        float t = 0.f;
#pragma unroll
        for (int i = 0; i < 8; ++i) t += s[i];
        partials[blockIdx.x] = t;
    }
}

__global__ __launch_bounds__(256) void byol_final_kernel(
        const float* __restrict__ partials, float* __restrict__ out) {
    float sum = 0.f;
#pragma unroll
    for (int j = 0; j < NBLOCKS / 256; ++j)
        sum += partials[threadIdx.x + 256 * j];

#pragma unroll
    for (int off = 32; off > 0; off >>= 1)
        sum += __shfl_down(sum, off, 64);

    __shared__ float s[4];
    const int wave = threadIdx.x >> 6;
    const int lane = threadIdx.x & 63;
    if (lane == 0) s[wave] = sum;
    __syncthreads();
    if (threadIdx.x == 0) {
        out[0] = (s[0] + s[1] + s[2] + s[3]) * (1.0f / ((float)NROWS * TEMP));
    }
}

extern "C" void kernel_launch(void* const* d_in, const int* in_sizes, int n_in,
                              void* d_out, int out_size, void* d_ws, size_t ws_size,
                              hipStream_t stream) {
    const float* a = (const float*)d_in[0];
    const float* b = (const float*)d_in[1];
    float* out = (float*)d_out;
    float* partials = (float*)d_ws;   // NBLOCKS floats = 8 KB

    byol_rows_kernel<<<NBLOCKS, 256, 0, stream>>>(a, b, partials);
    byol_final_kernel<<<1, 256, 0, stream>>>(partials, out);
}

// Round 4
// 141.569 us; speedup vs baseline: 1.0106x; 1.0106x over previous
//
#include <hip/hip_runtime.h>

#define TEMP 0.05f
#define EPS 1e-8f
#define NROWS 16384
#define DDIM 1024
#define NBLOCKS 1024          // 4 waves/block, 4 rows/wave -> 16 rows/block
#define ROWS_PER_WAVE 4

typedef float f32x4 __attribute__((ext_vector_type(4)));

__global__ __launch_bounds__(256) void byol_rows_kernel(
        const float* __restrict__ a, const float* __restrict__ b,
        float* __restrict__ partials) {
    const int wave = threadIdx.x >> 6;
    const int lane = threadIdx.x & 63;
    const int gwave = blockIdx.x * 4 + wave;
    const int row0  = gwave * ROWS_PER_WAVE;

    // One wave covers a full row: 64 lanes x 4 float4 = 1024 floats.
    const f32x4* a4 = (const f32x4*)(a) + (size_t)row0 * (DDIM / 4) + lane;
    const f32x4* b4 = (const f32x4*)(b) + (size_t)row0 * (DDIM / 4) + lane;
    const int rstride = DDIM / 4;   // float4s per row

    // Prologue: load row 0 of this wave's strip.
    f32x4 an[4], bn[4];
#pragma unroll
    for (int j = 0; j < 4; ++j) an[j] = __builtin_nontemporal_load(&a4[64 * j]);
#pragma unroll
    for (int j = 0; j < 4; ++j) bn[j] = __builtin_nontemporal_load(&b4[64 * j]);

    float loss = 0.f;

#pragma unroll
    for (int r = 0; r < ROWS_PER_WAVE; ++r) {
        // Rotate pipeline registers (unrolled -> renamed, no movs).
        f32x4 ac[4], bc[4];
#pragma unroll
        for (int j = 0; j < 4; ++j) { ac[j] = an[j]; bc[j] = bn[j]; }

        // Issue next row's loads BEFORE the reduction of the current row.
        if (r + 1 < ROWS_PER_WAVE) {
            const f32x4* a4n = a4 + (size_t)(r + 1) * rstride;
            const f32x4* b4n = b4 + (size_t)(r + 1) * rstride;
#pragma unroll
            for (int j = 0; j < 4; ++j) an[j] = __builtin_nontemporal_load(&a4n[64 * j]);
#pragma unroll
            for (int j = 0; j < 4; ++j) bn[j] = __builtin_nontemporal_load(&b4n[64 * j]);
        }

        float dot = 0.f, aa = 0.f, bb = 0.f;
#pragma unroll
        for (int j = 0; j < 4; ++j) {
            dot += ac[j].x * bc[j].x + ac[j].y * bc[j].y
                 + ac[j].z * bc[j].z + ac[j].w * bc[j].w;
            aa  += ac[j].x * ac[j].x + ac[j].y * ac[j].y
                 + ac[j].z * ac[j].z + ac[j].w * ac[j].w;
            bb  += bc[j].x * bc[j].x + bc[j].y * bc[j].y
                 + bc[j].z * bc[j].z + bc[j].w * bc[j].w;
        }

        // Full-wave butterfly; overlaps the in-flight loads of row r+1.
#pragma unroll
        for (int off = 32; off > 0; off >>= 1) {
            dot += __shfl_xor(dot, off, 64);
            aa  += __shfl_xor(aa,  off, 64);
            bb  += __shfl_xor(bb,  off, 64);
        }

        float n1 = fmaxf(sqrtf(aa), EPS);
        float n2 = fmaxf(sqrtf(bb), EPS);
        loss += 2.0f - 2.0f * (dot / (n1 * n2));
    }

    __shared__ float s[4];
    if (lane == 0) s[wave] = loss;
    __syncthreads();
    if (threadIdx.x == 0) {
        partials[blockIdx.x] = s[0] + s[1] + s[2] + s[3];
    }
}

__global__ __launch_bounds__(256) void byol_final_kernel(
        const float* __restrict__ partials, float* __restrict__ out) {
    float sum = 0.f;
#pragma unroll
    for (int j = 0; j < NBLOCKS / 256; ++j)
        sum += partials[threadIdx.x + 256 * j];

#pragma unroll
    for (int off = 32; off > 0; off >>= 1)
        sum += __shfl_down(sum, off, 64);

    __shared__ float s[4];
    const int wave = threadIdx.x >> 6;
    const int lane = threadIdx.x & 63;
    if (lane == 0) s[wave] = sum;
    __syncthreads();
    if (threadIdx.x == 0) {
        out[0] = (s[0] + s[1] + s[2] + s[3]) * (1.0f / ((float)NROWS * TEMP));
    }
}

extern "C" void kernel_launch(void* const* d_in, const int* in_sizes, int n_in,
                              void* d_out, int out_size, void* d_ws, size_t ws_size,
                              hipStream_t stream) {
    const float* a = (const float*)d_in[0];
    const float* b = (const float*)d_in[1];
    float* out = (float*)d_out;
    float* partials = (float*)d_ws;   // NBLOCKS floats = 4 KB

    byol_rows_kernel<<<NBLOCKS, 256, 0, stream>>>(a, b, partials);
    byol_final_kernel<<<1, 256, 0, stream>>>(partials, out);
}